// Round 5
// baseline (1076.692 us; speedup 1.0000x reference)
//
#include <hip/hip_runtime.h>

typedef unsigned short u16;
typedef unsigned int u32;
typedef __bf16 bf16x8 __attribute__((ext_vector_type(8)));
typedef float f32x4 __attribute__((ext_vector_type(4)));

#define BM 128
#define BN 128
#define BK 64     // Tier-A K-tile
#define BKB 32    // Tier-B K-tile
#define KDIM 2048
#define NDIM 512
#define MDIM 65536
#define LROW 40   // Tier-B padded LDS row (ushorts)

typedef __attribute__((address_space(3))) void lds_void;
typedef const __attribute__((address_space(1))) void glb_void;
#define LOAD_LDS16(g, l) \
  __builtin_amdgcn_global_load_lds((glb_void*)(g), (lds_void*)(l), 16, 0, 0)

__device__ __forceinline__ u16 f2bf(float f) {
  u32 u = __float_as_uint(f);
  u += 0x7FFFu + ((u >> 16) & 1u);   // round-to-nearest-even
  return (u16)(u >> 16);
}

// ---- W_enc (2048x512 f32) -> WT (512x2048 bf16), Tier-B only ----
__global__ __launch_bounds__(256) void wenc_t(const float* __restrict__ W, u16* __restrict__ WT) {
  const int n = blockIdx.x;  // 0..511
  for (int k = threadIdx.x; k < KDIM; k += 256)
    WT[n * KDIM + k] = f2bf(W[k * NDIM + n]);
}

// ---- W_enc -> Bp packed in MFMA B-fragment order (Tier A) ----
// u16 flat index: (((g16*32 + kk)*2 + h)*64 + lane)*8 ; lane=(quad<<4)|l15
// element j of lane's 8: B[n = g16*16 + l15][k = kk*64 + h*32 + quad*8 + j]
__global__ __launch_bounds__(256) void wenc_pack(const float* __restrict__ W,
                                                 u16* __restrict__ Bp) {
  const int t = blockIdx.x * 256 + threadIdx.x;  // 0..131071 (uint4 index)
  const int lane = t & 63;
  const int h = (t >> 6) & 1;
  const int kk = (t >> 7) & 31;
  const int g16 = t >> 12;
  const int l15 = lane & 15, quad = lane >> 4;
  const int n = g16 * 16 + l15;
  const int k0 = kk * 64 + h * 32 + quad * 8;
  u16 o[8];
#pragma unroll
  for (int j = 0; j < 8; j++) o[j] = f2bf(W[(size_t)(k0 + j) * NDIM + n]);
  *(uint4*)(Bp + (size_t)t * 8) = *(const uint4*)o;
}

// ---- att2[b,a] = dec[b,:]@W_dec[:,a] + b_dec[a] + b_enc[a] ----
__global__ __launch_bounds__(256) void att2_kernel(const float* __restrict__ dec,
                                                   const float* __restrict__ Wd,
                                                   const float* __restrict__ bd,
                                                   const float* __restrict__ be,
                                                   float* __restrict__ att2) {
  const int idx = blockIdx.x * 256 + threadIdx.x;  // 32768
  const int b = idx >> 9, a = idx & 511;
  float s = bd[a] + be[a];
  const float* dp = dec + b * 512;
#pragma unroll 8
  for (int d = 0; d < 512; d++) s += dp[d] * Wd[d * NDIM + a];
  att2[idx] = s;
}

// ---- enc fp32 -> bf16 streaming convert (2^27 elements) ----
__global__ __launch_bounds__(256) void enc_to_bf16(const float* __restrict__ src,
                                                   u16* __restrict__ dst) {
  const size_t tidg = (size_t)blockIdx.x * 256 + threadIdx.x;  // 2M threads
#pragma unroll
  for (int it = 0; it < 8; it++) {
    const size_t base = ((size_t)it * 16777216) + tidg * 8;    // float index
    const float4 x = *(const float4*)(src + base);
    const float4 y = *(const float4*)(src + base + 4);
    uint4 o;
    o.x = f2bf(x.x) | ((u32)f2bf(x.y) << 16);
    o.y = f2bf(x.z) | ((u32)f2bf(x.w) << 16);
    o.z = f2bf(y.x) | ((u32)f2bf(y.y) << 16);
    o.w = f2bf(y.z) | ((u32)f2bf(y.w) << 16);
    *(uint4*)(dst + base) = o;
  }
}

// ---- Tier A GEMM: A-only LDS (DMA + XOR swizzle), B direct from packed L2 ----
__global__ __launch_bounds__(256) void gemm_logits_a(const u16* __restrict__ A,   // 65536x2048 bf16
                                                     const u16* __restrict__ Bp,  // packed 2MB
                                                     const float* __restrict__ att2,
                                                     const float* __restrict__ Wfull,
                                                     float* __restrict__ partial) {
  __shared__ u16 As[BM * BK];   // 16 KB
  __shared__ float lds_logit[BM];

  const int tid = threadIdx.x;
  // XCD swizzle: flat = x + 8*(nb + 4*g), mb = g*8 + x  -> 4 nb-blocks of one
  // mb are 8 apart in flat index (same XCD under %8 round-robin dispatch)
  const int flat = blockIdx.x;           // 0..2047
  const int x = flat & 7;
  const int nb = (flat >> 3) & 3;
  const int mb = ((flat >> 5) << 3) + x; // 0..511
  const int rowBase = mb * BM;
  const int colBase = nb * BN;
  const int b = rowBase >> 10;

  if (tid < BM) lds_logit[tid] = 0.f;

  const int lane = tid & 63, wid = tid >> 6;
  const int wr = (wid >> 1) * 64, wc = (wid & 1) * 64;
  const int quad = lane >> 4, l15 = lane & 15;

  float att2v[4], wfv[4];
#pragma unroll
  for (int j = 0; j < 4; j++) {
    const int g = colBase + wc + j * 16 + l15;
    att2v[j] = att2[b * NDIM + g];
    wfv[j] = Wfull[g];
  }

  // A staging: 4 chunks/thread; chunk c = s*256+tid -> row c>>3, stored k-chunk c&7,
  // global k-chunk (c&7)^(r&7)
  const u16* AgS[4];
  u16* AsD[4];
#pragma unroll
  for (int s = 0; s < 4; s++) {
    const int c = s * 256 + tid;
    const int r = c >> 3;
    const int kc = (c & 7) ^ (r & 7);
    AgS[s] = A + (size_t)(rowBase + r) * KDIM + kc * 8;
    AsD[s] = &As[c * 8];
  }

  // B fragment base (uint4 index): (g16_0+j)*4096 + kk*128 + h*64 + lane
  const int g16_0 = (colBase + wc) >> 4;
  const uint4* BpV = (const uint4*)Bp;

  f32x4 acc[4][4];
#pragma unroll
  for (int i = 0; i < 4; i++)
#pragma unroll
    for (int j = 0; j < 4; j++) acc[i][j] = (f32x4)0.f;

  for (int kk = 0; kk < KDIM / BK; kk++) {
    const int ko = kk * BK;
    __syncthreads();
#pragma unroll
    for (int s = 0; s < 4; s++) LOAD_LDS16(AgS[s] + ko, AsD[s]);
    // B frags: coalesced 1KB wave loads from L2-resident packed buffer;
    // latency hides behind the A-DMA barrier drain
    uint4 braw[2][4];
#pragma unroll
    for (int h = 0; h < 2; h++)
#pragma unroll
      for (int j = 0; j < 4; j++)
        braw[h][j] = BpV[(g16_0 + j) * 4096 + kk * 128 + h * 64 + lane];
    __syncthreads();

    bf16x8 afr[2][4];
#pragma unroll
    for (int h = 0; h < 2; h++)
#pragma unroll
      for (int i = 0; i < 4; i++) {
        const int m = wr + i * 16 + l15;
        afr[h][i] = *(const bf16x8*)&As[m * BK + ((((h << 2) | quad) ^ (l15 & 7)) << 3)];
      }
#pragma unroll
    for (int h = 0; h < 2; h++)
#pragma unroll
      for (int i = 0; i < 4; i++)
#pragma unroll
        for (int j = 0; j < 4; j++)
          acc[i][j] = __builtin_amdgcn_mfma_f32_16x16x32_bf16(
              afr[h][i], *(const bf16x8*)&braw[h][j], acc[i][j], 0, 0, 0);
  }

#pragma unroll
  for (int i = 0; i < 4; i++) {
#pragma unroll
    for (int r = 0; r < 4; r++) {
      float s = 0.f;
#pragma unroll
      for (int j = 0; j < 4; j++) {
        float v = acc[i][j][r] + att2v[j];
        v = v > 0.f ? v : 0.f;
        s += v * wfv[j];
      }
      s += __shfl_xor(s, 1, 64);
      s += __shfl_xor(s, 2, 64);
      s += __shfl_xor(s, 4, 64);
      s += __shfl_xor(s, 8, 64);
      if (l15 == 0) atomicAdd(&lds_logit[wr + i * 16 + quad * 4 + r], s);
    }
  }
  __syncthreads();
  if (tid < BM) partial[(size_t)nb * MDIM + rowBase + tid] = lds_logit[tid];
}

// ---- Tier B fallback GEMM (inline fp32->bf16 staging) ----
// 1-D grid + the SAME XCD swizzle as Tier A: the 4 nb-blocks sharing an A
// row-panel sit 8 apart in flat index -> same XCD -> A-panel L2 reuse
// (the old dim3(4,512) grid put them on 4 different XCDs -> 4x A HBM traffic).
__global__ __launch_bounds__(256, 2) void gemm_logits_b(const float* __restrict__ enc,
                                                        const u16* __restrict__ WT,
                                                        const float* __restrict__ att2,
                                                        const float* __restrict__ Wfull,
                                                        float* __restrict__ partial) {
  __shared__ u16 As[BM * LROW];
  __shared__ u16 Bs[BN * LROW];
  __shared__ float lds_logit[BM];

  const int tid = threadIdx.x;
  const int flat = blockIdx.x;           // 0..2047
  const int x = flat & 7;
  const int nb = (flat >> 3) & 3;
  const int mb = ((flat >> 5) << 3) + x; // 0..511
  const int rowBase = mb * BM, colBase = nb * BN;
  const int b = rowBase >> 10;
  if (tid < BM) lds_logit[tid] = 0.f;
  const int lane = tid & 63, wid = tid >> 6;
  const int wr = (wid >> 1) * 64, wc = (wid & 1) * 64;
  const int quad = lane >> 4, l15 = lane & 15;

  float att2v[4], wfv[4];
#pragma unroll
  for (int j = 0; j < 4; j++) {
    const int g = colBase + wc + j * 16 + l15;
    att2v[j] = att2[b * NDIM + g];
    wfv[j] = Wfull[g];
  }
  const int srow = tid >> 1, shalf = tid & 1;
  const float* Ag = enc + (size_t)(rowBase + srow) * KDIM + shalf * 16;
  const u16* Bg = WT + (size_t)(colBase + srow) * KDIM + shalf * 16;

  f32x4 acc[4][4];
#pragma unroll
  for (int i = 0; i < 4; i++)
#pragma unroll
    for (int j = 0; j < 4; j++) acc[i][j] = (f32x4)0.f;

  float4 a0, a1, a2, a3;
  uint4 bb0, bb1;
  auto loadA = [&](int k0) {
    const float* p = Ag + k0;
    a0 = *(const float4*)(p);
    a1 = *(const float4*)(p + 4);
    a2 = *(const float4*)(p + 8);
    a3 = *(const float4*)(p + 12);
  };
  auto loadB = [&](int k0) {
    const u16* p = Bg + k0;
    bb0 = *(const uint4*)(p);
    bb1 = *(const uint4*)(p + 8);
  };
  loadA(0);
  loadB(0);
  u16* AsW = &As[srow * LROW + shalf * 16];
  u16* BsW = &Bs[srow * LROW + shalf * 16];
  const u16* aRd = &As[(wr + l15) * LROW + quad * 8];
  const u16* bRd = &Bs[(wc + l15) * LROW + quad * 8];

  for (int kk = 0; kk < KDIM / BKB; kk++) {
    __syncthreads();
    u32 w0 = f2bf(a0.x) | ((u32)f2bf(a0.y) << 16);
    u32 w1 = f2bf(a0.z) | ((u32)f2bf(a0.w) << 16);
    u32 w2 = f2bf(a1.x) | ((u32)f2bf(a1.y) << 16);
    u32 w3 = f2bf(a1.z) | ((u32)f2bf(a1.w) << 16);
    u32 w4 = f2bf(a2.x) | ((u32)f2bf(a2.y) << 16);
    u32 w5 = f2bf(a2.z) | ((u32)f2bf(a2.w) << 16);
    u32 w6 = f2bf(a3.x) | ((u32)f2bf(a3.y) << 16);
    u32 w7 = f2bf(a3.z) | ((u32)f2bf(a3.w) << 16);
    *(uint4*)AsW = make_uint4(w0, w1, w2, w3);
    *(uint4*)(AsW + 8) = make_uint4(w4, w5, w6, w7);
    *(uint4*)BsW = bb0;
    *(uint4*)(BsW + 8) = bb1;
    __syncthreads();
    if (kk + 1 < KDIM / BKB) {
      loadA((kk + 1) * BKB);
      loadB((kk + 1) * BKB);
    }
    bf16x8 afr[4], bfr[4];
#pragma unroll
    for (int i = 0; i < 4; i++) afr[i] = *(const bf16x8*)(aRd + i * 16 * LROW);
#pragma unroll
    for (int j = 0; j < 4; j++) bfr[j] = *(const bf16x8*)(bRd + j * 16 * LROW);
#pragma unroll
    for (int i = 0; i < 4; i++)
#pragma unroll
      for (int j = 0; j < 4; j++)
        acc[i][j] = __builtin_amdgcn_mfma_f32_16x16x32_bf16(afr[i], bfr[j], acc[i][j], 0, 0, 0);
  }
#pragma unroll
  for (int i = 0; i < 4; i++) {
#pragma unroll
    for (int r = 0; r < 4; r++) {
      float s = 0.f;
#pragma unroll
      for (int j = 0; j < 4; j++) {
        float v = acc[i][j][r] + att2v[j];
        v = v > 0.f ? v : 0.f;
        s += v * wfv[j];
      }
      s += __shfl_xor(s, 1, 64);
      s += __shfl_xor(s, 2, 64);
      s += __shfl_xor(s, 4, 64);
      s += __shfl_xor(s, 8, 64);
      if (l15 == 0) atomicAdd(&lds_logit[wr + i * 16 + quad * 4 + r], s);
    }
  }
  __syncthreads();
  if (tid < BM) partial[(size_t)nb * MDIM + rowBase + tid] = lds_logit[tid];
}

// ---- softmax over L=1024 per batch ----
__global__ __launch_bounds__(256) void softmax_kernel(const float* __restrict__ partial,
                                                      const float* __restrict__ b_full,
                                                      float* __restrict__ att_out) {
  const int b = blockIdx.x, tid = threadIdx.x;
  const int lane = tid & 63, wid = tid >> 6;
  __shared__ float red[4];
  const float bf0 = b_full[0];
  float v[4];
  float m = -3.4e38f;
#pragma unroll
  for (int c = 0; c < 4; c++) {
    const int idx = b * 1024 + c * 256 + tid;
    float s = partial[idx] + partial[MDIM + idx] + partial[2 * MDIM + idx] +
              partial[3 * MDIM + idx] + bf0;
    v[c] = s;
    m = fmaxf(m, s);
  }
#pragma unroll
  for (int o = 1; o < 64; o <<= 1) m = fmaxf(m, __shfl_xor(m, o, 64));
  if (lane == 0) red[wid] = m;
  __syncthreads();
  m = fmaxf(fmaxf(red[0], red[1]), fmaxf(red[2], red[3]));
  __syncthreads();
  float s = 0.f;
#pragma unroll
  for (int c = 0; c < 4; c++) {
    v[c] = expf(v[c] - m);
    s += v[c];
  }
#pragma unroll
  for (int o = 1; o < 64; o <<= 1) s += __shfl_xor(s, o, 64);
  if (lane == 0) red[wid] = s;
  __syncthreads();
  const float inv = 1.0f / (red[0] + red[1] + red[2] + red[3]);
#pragma unroll
  for (int c = 0; c < 4; c++) att_out[b * 1024 + c * 256 + tid] = v[c] * inv;
}

// ---- Tier A context partials: 2048 blocks = 64b x 2ec x 16lc ----
__global__ __launch_bounds__(256) void ctx_partial_a(const float* __restrict__ enc,
                                                     const float* __restrict__ att,
                                                     float* __restrict__ ctxp) {
  const int x = blockIdx.x;
  const int lc = x & 15, ec = (x >> 4) & 1, b = x >> 5;
  const int tid = threadIdx.x;
  __shared__ float aw[64];
  if (tid < 64) aw[tid] = att[b * 1024 + lc * 64 + tid];
  __syncthreads();
  const int e0 = ec * 1024 + tid * 4;
  float4 acc = {0.f, 0.f, 0.f, 0.f};
  const float* base = enc + (size_t)b * 1024 * 2048 + (size_t)(lc * 64) * 2048 + e0;
#pragma unroll 16
  for (int l = 0; l < 64; l++) {
    const float w = aw[l];
    const float4 v = *(const float4*)(base + (size_t)l * 2048);
    acc.x += w * v.x;
    acc.y += w * v.y;
    acc.z += w * v.z;
    acc.w += w * v.w;
  }
  *(float4*)(ctxp + (size_t)lc * 131072 + b * 2048 + e0) = acc;
}

__global__ __launch_bounds__(256) void ctx_reduce_a(const float* __restrict__ ctxp,
                                                    float* __restrict__ out) {
  const int i = blockIdx.x * 256 + threadIdx.x;  // 131072
  float s = 0.f;
#pragma unroll
  for (int lc = 0; lc < 16; lc++) s += ctxp[(size_t)lc * 131072 + i];
  out[i] = s;
}

// ---- Tier B context ----
__global__ __launch_bounds__(256) void ctx_partial_b(const float* __restrict__ enc,
                                                     const float* __restrict__ att,
                                                     float* __restrict__ ctxp) {
  const int x = blockIdx.x;
  const int lc = x & 3, ec = (x >> 2) & 1, b = x >> 3;
  const int tid = threadIdx.x;
  __shared__ float aw[256];
  aw[tid] = att[b * 1024 + lc * 256 + tid];
  __syncthreads();
  const int e0 = ec * 1024 + tid * 4;
  float4 acc = {0.f, 0.f, 0.f, 0.f};
  const float* base = enc + (size_t)b * 1024 * 2048 + (size_t)(lc * 256) * 2048 + e0;
#pragma unroll 4
  for (int l = 0; l < 256; l++) {
    const float w = aw[l];
    const float4 v = *(const float4*)(base + (size_t)l * 2048);
    acc.x += w * v.x;
    acc.y += w * v.y;
    acc.z += w * v.z;
    acc.w += w * v.w;
  }
  *(float4*)(ctxp + (size_t)lc * 131072 + b * 2048 + e0) = acc;
}

__global__ __launch_bounds__(256) void ctx_reduce_b(const float* __restrict__ ctxp,
                                                    float* __restrict__ out) {
  const int i = blockIdx.x * 256 + threadIdx.x;
  out[i] = ctxp[i] + ctxp[131072 + i] + ctxp[262144 + i] + ctxp[393216 + i];
}

extern "C" void kernel_launch(void* const* d_in, const int* in_sizes, int n_in,
                              void* d_out, int out_size, void* d_ws, size_t ws_size,
                              hipStream_t stream) {
  const float* enc    = (const float*)d_in[0];
  const float* dec    = (const float*)d_in[1];
  const float* W_enc  = (const float*)d_in[2];
  const float* b_enc  = (const float*)d_in[3];
  const float* W_dec  = (const float*)d_in[4];
  const float* b_dec  = (const float*)d_in[5];
  const float* W_full = (const float*)d_in[6];
  const float* b_full = (const float*)d_in[7];
  float* out = (float*)d_out;
  char* ws = (char*)d_ws;

  const size_t MB = 1u << 20;
  const size_t needA = 256 * MB + 2 * MB + MB + MB;  // encb + Bp + att2/pad + partial

  if (ws_size >= needA) {
    // Tier A layout: [0,256MB) encb (aliased by ctxp 8MB after gemm);
    // [256MB,258MB) Bp; [258MB,+128KB) att2; then partial (1MB)
    u16* encb = (u16*)ws;
    float* ctxp = (float*)ws;
    u16* Bp = (u16*)(ws + 256 * MB);
    float* att2 = (float*)(ws + 258 * MB);
    float* partial = (float*)(ws + 258 * MB + 128 * 1024);

    wenc_pack<<<512, 256, 0, stream>>>(W_enc, Bp);
    att2_kernel<<<128, 256, 0, stream>>>(dec, W_dec, b_dec, b_enc, att2);
    enc_to_bf16<<<8192, 256, 0, stream>>>(enc, encb);
    gemm_logits_a<<<2048, 256, 0, stream>>>(encb, Bp, att2, W_full, partial);
    softmax_kernel<<<64, 256, 0, stream>>>(partial, b_full, out + 131072);
    ctx_partial_a<<<2048, 256, 0, stream>>>(enc, out + 131072, ctxp);
    ctx_reduce_a<<<512, 256, 0, stream>>>(ctxp, out);
  } else {
    // Tier B: [0,2MB) WT / ctxp alias; [2MB,+128KB) att2; then partial
    u16* WT = (u16*)ws;
    float* ctxp = (float*)ws;
    float* att2 = (float*)(ws + 2 * MB);
    float* partial = (float*)(ws + 2 * MB + 128 * 1024);

    wenc_t<<<512, 256, 0, stream>>>(W_enc, WT);
    att2_kernel<<<128, 256, 0, stream>>>(dec, W_dec, b_dec, b_enc, att2);
    gemm_logits_b<<<2048, 256, 0, stream>>>(enc, WT, att2, W_full, partial);
    softmax_kernel<<<64, 256, 0, stream>>>(partial, b_full, out + 131072);
    ctx_partial_b<<<512, 256, 0, stream>>>(enc, out + 131072, ctxp);
    ctx_reduce_b<<<512, 256, 0, stream>>>(ctxp, out);
  }
}

// Round 12
// 961.161 us; speedup vs baseline: 1.1202x; 1.1202x over previous
//
#include <hip/hip_runtime.h>

typedef unsigned short u16;
typedef unsigned int u32;
typedef __bf16 bf16x8 __attribute__((ext_vector_type(8)));
typedef float f32x4 __attribute__((ext_vector_type(4)));

#define BM 128
#define BN 128
#define BK 64     // fused-GEMM K-tile
#define BKB 32    // Tier-B K-tile
#define KDIM 2048
#define NDIM 512
#define MDIM 65536
#define LROW 40   // Tier-B padded LDS row (ushorts)

__device__ __forceinline__ u16 f2bf(float f) {
  u32 u = __float_as_uint(f);
  u += 0x7FFFu + ((u >> 16) & 1u);   // round-to-nearest-even
  return (u16)(u >> 16);
}

// ---- W_enc (2048x512 f32) -> WT (512x2048 bf16), Tier-B only ----
__global__ __launch_bounds__(256) void wenc_t(const float* __restrict__ W, u16* __restrict__ WT) {
  const int n = blockIdx.x;  // 0..511
  for (int k = threadIdx.x; k < KDIM; k += 256)
    WT[n * KDIM + k] = f2bf(W[k * NDIM + n]);
}

// ---- W_enc -> Bp packed in MFMA B-fragment order ----
// u16 flat index: (((g16*32 + kk)*2 + h)*64 + lane)*8 ; lane=(quad<<4)|l15
// element j of lane's 8: B[n = g16*16 + l15][k = kk*64 + h*32 + quad*8 + j]
__global__ __launch_bounds__(256) void wenc_pack(const float* __restrict__ W,
                                                 u16* __restrict__ Bp) {
  const int t = blockIdx.x * 256 + threadIdx.x;  // 0..131071 (uint4 index)
  const int lane = t & 63;
  const int h = (t >> 6) & 1;
  const int kk = (t >> 7) & 31;
  const int g16 = t >> 12;
  const int l15 = lane & 15, quad = lane >> 4;
  const int n = g16 * 16 + l15;
  const int k0 = kk * 64 + h * 32 + quad * 8;
  u16 o[8];
#pragma unroll
  for (int j = 0; j < 8; j++) o[j] = f2bf(W[(size_t)(k0 + j) * NDIM + n]);
  *(uint4*)(Bp + (size_t)t * 8) = *(const uint4*)o;
}

// ---- att2[b,a] = dec[b,:]@W_dec[:,a] + b_dec[a] + b_enc[a] ----
__global__ __launch_bounds__(256) void att2_kernel(const float* __restrict__ dec,
                                                   const float* __restrict__ Wd,
                                                   const float* __restrict__ bd,
                                                   const float* __restrict__ be,
                                                   float* __restrict__ att2) {
  const int idx = blockIdx.x * 256 + threadIdx.x;  // 32768
  const int b = idx >> 9, a = idx & 511;
  float s = bd[a] + be[a];
  const float* dp = dec + b * 512;
#pragma unroll 8
  for (int d = 0; d < 512; d++) s += dp[d] * Wd[d * NDIM + a];
  att2[idx] = s;
}

// ---- Fused GEMM: fp32 A staged + converted inline (kills the enc_to_bf16 pass).
// LDS layout, XOR swizzle, fragment reads, MFMA loop, epilogue are byte-identical
// to the verified DMA version; only the staging writes (reg-stage + f2bf + ds_write)
// differ, producing the exact same LDS bytes -> bit-identical logits.
__global__ __launch_bounds__(256) void gemm_logits_f(const float* __restrict__ A,   // enc 65536x2048 f32
                                                     const u16* __restrict__ Bp,    // packed 2MB
                                                     const float* __restrict__ att2,
                                                     const float* __restrict__ Wfull,
                                                     float* __restrict__ partial) {
  __shared__ u16 As[BM * BK];   // 16 KB
  __shared__ float lds_logit[BM];

  const int tid = threadIdx.x;
  // XCD swizzle: flat = x + 8*(nb + 4*g), mb = g*8 + x
  const int flat = blockIdx.x;           // 0..2047
  const int x = flat & 7;
  const int nb = (flat >> 3) & 3;
  const int mb = ((flat >> 5) << 3) + x; // 0..511
  const int rowBase = mb * BM;
  const int colBase = nb * BN;
  const int b = rowBase >> 10;

  if (tid < BM) lds_logit[tid] = 0.f;

  const int lane = tid & 63, wid = tid >> 6;
  const int wr = (wid >> 1) * 64, wc = (wid & 1) * 64;
  const int quad = lane >> 4, l15 = lane & 15;

  float att2v[4], wfv[4];
#pragma unroll
  for (int j = 0; j < 4; j++) {
    const int g = colBase + wc + j * 16 + l15;
    att2v[j] = att2[b * NDIM + g];
    wfv[j] = Wfull[g];
  }

  // A staging: chunk c = s*256+tid -> row r=c>>3, stored k-chunk c&7,
  // global k-chunk g=(c&7)^(r&7)  (same mapping as the DMA version)
  const float* AgF[4];
  u16* AsD[4];
#pragma unroll
  for (int s = 0; s < 4; s++) {
    const int c = s * 256 + tid;
    const int r = c >> 3;
    const int g = (c & 7) ^ (r & 7);
    AgF[s] = A + (size_t)(rowBase + r) * KDIM + g * 8;
    AsD[s] = &As[c * 8];
  }

  const int g16_0 = (colBase + wc) >> 4;
  const uint4* BpV = (const uint4*)Bp;

  f32x4 acc[4][4];
#pragma unroll
  for (int i = 0; i < 4; i++)
#pragma unroll
    for (int j = 0; j < 4; j++) acc[i][j] = (f32x4)0.f;

  // fp32 prefetch registers (8 x float4 = 32 VGPR)
  float4 pa0[4], pa1[4];
  auto loadA = [&](int ko) {
#pragma unroll
    for (int s = 0; s < 4; s++) {
      pa0[s] = *(const float4*)(AgF[s] + ko);
      pa1[s] = *(const float4*)(AgF[s] + ko + 4);
    }
  };
  loadA(0);

  for (int kk = 0; kk < KDIM / BK; kk++) {
    __syncthreads();
    // B frags first: L2 latency overlaps the convert VALU work below
    uint4 braw[2][4];
#pragma unroll
    for (int h = 0; h < 2; h++)
#pragma unroll
      for (int j = 0; j < 4; j++)
        braw[h][j] = BpV[(g16_0 + j) * 4096 + kk * 128 + h * 64 + lane];
    // convert + store A chunks (same bytes/addresses the DMA version produced)
#pragma unroll
    for (int s = 0; s < 4; s++) {
      uint4 o;
      o.x = f2bf(pa0[s].x) | ((u32)f2bf(pa0[s].y) << 16);
      o.y = f2bf(pa0[s].z) | ((u32)f2bf(pa0[s].w) << 16);
      o.z = f2bf(pa1[s].x) | ((u32)f2bf(pa1[s].y) << 16);
      o.w = f2bf(pa1[s].z) | ((u32)f2bf(pa1[s].w) << 16);
      *(uint4*)AsD[s] = o;
    }
    __syncthreads();
    if (kk + 1 < KDIM / BK) loadA((kk + 1) * BK);  // prefetch next fp32 tile

    bf16x8 afr[2][4];
#pragma unroll
    for (int h = 0; h < 2; h++)
#pragma unroll
      for (int i = 0; i < 4; i++) {
        const int m = wr + i * 16 + l15;
        afr[h][i] = *(const bf16x8*)&As[m * BK + ((((h << 2) | quad) ^ (l15 & 7)) << 3)];
      }
#pragma unroll
    for (int h = 0; h < 2; h++)
#pragma unroll
      for (int i = 0; i < 4; i++)
#pragma unroll
        for (int j = 0; j < 4; j++)
          acc[i][j] = __builtin_amdgcn_mfma_f32_16x16x32_bf16(
              afr[h][i], *(const bf16x8*)&braw[h][j], acc[i][j], 0, 0, 0);
  }

#pragma unroll
  for (int i = 0; i < 4; i++) {
#pragma unroll
    for (int r = 0; r < 4; r++) {
      float s = 0.f;
#pragma unroll
      for (int j = 0; j < 4; j++) {
        float v = acc[i][j][r] + att2v[j];
        v = v > 0.f ? v : 0.f;
        s += v * wfv[j];
      }
      s += __shfl_xor(s, 1, 64);
      s += __shfl_xor(s, 2, 64);
      s += __shfl_xor(s, 4, 64);
      s += __shfl_xor(s, 8, 64);
      if (l15 == 0) atomicAdd(&lds_logit[wr + i * 16 + quad * 4 + r], s);
    }
  }
  __syncthreads();
  if (tid < BM) partial[(size_t)nb * MDIM + rowBase + tid] = lds_logit[tid];
}

// ---- Tier B fallback GEMM (inline fp32->bf16 staging, BKB=32) ----
__global__ __launch_bounds__(256, 2) void gemm_logits_b(const float* __restrict__ enc,
                                                        const u16* __restrict__ WT,
                                                        const float* __restrict__ att2,
                                                        const float* __restrict__ Wfull,
                                                        float* __restrict__ partial) {
  __shared__ u16 As[BM * LROW];
  __shared__ u16 Bs[BN * LROW];
  __shared__ float lds_logit[BM];

  const int tid = threadIdx.x;
  const int flat = blockIdx.x;           // 0..2047
  const int x = flat & 7;
  const int nb = (flat >> 3) & 3;
  const int mb = ((flat >> 5) << 3) + x; // 0..511
  const int rowBase = mb * BM, colBase = nb * BN;
  const int b = rowBase >> 10;
  if (tid < BM) lds_logit[tid] = 0.f;
  const int lane = tid & 63, wid = tid >> 6;
  const int wr = (wid >> 1) * 64, wc = (wid & 1) * 64;
  const int quad = lane >> 4, l15 = lane & 15;

  float att2v[4], wfv[4];
#pragma unroll
  for (int j = 0; j < 4; j++) {
    const int g = colBase + wc + j * 16 + l15;
    att2v[j] = att2[b * NDIM + g];
    wfv[j] = Wfull[g];
  }
  const int srow = tid >> 1, shalf = tid & 1;
  const float* Ag = enc + (size_t)(rowBase + srow) * KDIM + shalf * 16;
  const u16* Bg = WT + (size_t)(colBase + srow) * KDIM + shalf * 16;

  f32x4 acc[4][4];
#pragma unroll
  for (int i = 0; i < 4; i++)
#pragma unroll
    for (int j = 0; j < 4; j++) acc[i][j] = (f32x4)0.f;

  float4 a0, a1, a2, a3;
  uint4 bb0, bb1;
  auto loadA = [&](int k0) {
    const float* p = Ag + k0;
    a0 = *(const float4*)(p);
    a1 = *(const float4*)(p + 4);
    a2 = *(const float4*)(p + 8);
    a3 = *(const float4*)(p + 12);
  };
  auto loadB = [&](int k0) {
    const u16* p = Bg + k0;
    bb0 = *(const uint4*)(p);
    bb1 = *(const uint4*)(p + 8);
  };
  loadA(0);
  loadB(0);
  u16* AsW = &As[srow * LROW + shalf * 16];
  u16* BsW = &Bs[srow * LROW + shalf * 16];
  const u16* aRd = &As[(wr + l15) * LROW + quad * 8];
  const u16* bRd = &Bs[(wc + l15) * LROW + quad * 8];

  for (int kk = 0; kk < KDIM / BKB; kk++) {
    __syncthreads();
    u32 w0 = f2bf(a0.x) | ((u32)f2bf(a0.y) << 16);
    u32 w1 = f2bf(a0.z) | ((u32)f2bf(a0.w) << 16);
    u32 w2 = f2bf(a1.x) | ((u32)f2bf(a1.y) << 16);
    u32 w3 = f2bf(a1.z) | ((u32)f2bf(a1.w) << 16);
    u32 w4 = f2bf(a2.x) | ((u32)f2bf(a2.y) << 16);
    u32 w5 = f2bf(a2.z) | ((u32)f2bf(a2.w) << 16);
    u32 w6 = f2bf(a3.x) | ((u32)f2bf(a3.y) << 16);
    u32 w7 = f2bf(a3.z) | ((u32)f2bf(a3.w) << 16);
    *(uint4*)AsW = make_uint4(w0, w1, w2, w3);
    *(uint4*)(AsW + 8) = make_uint4(w4, w5, w6, w7);
    *(uint4*)BsW = bb0;
    *(uint4*)(BsW + 8) = bb1;
    __syncthreads();
    if (kk + 1 < KDIM / BKB) {
      loadA((kk + 1) * BKB);
      loadB((kk + 1) * BKB);
    }
    bf16x8 afr[4], bfr[4];
#pragma unroll
    for (int i = 0; i < 4; i++) afr[i] = *(const bf16x8*)(aRd + i * 16 * LROW);
#pragma unroll
    for (int j = 0; j < 4; j++) bfr[j] = *(const bf16x8*)(bRd + j * 16 * LROW);
#pragma unroll
    for (int i = 0; i < 4; i++)
#pragma unroll
      for (int j = 0; j < 4; j++)
        acc[i][j] = __builtin_amdgcn_mfma_f32_16x16x32_bf16(afr[i], bfr[j], acc[i][j], 0, 0, 0);
  }
#pragma unroll
  for (int i = 0; i < 4; i++) {
#pragma unroll
    for (int r = 0; r < 4; r++) {
      float s = 0.f;
#pragma unroll
      for (int j = 0; j < 4; j++) {
        float v = acc[i][j][r] + att2v[j];
        v = v > 0.f ? v : 0.f;
        s += v * wfv[j];
      }
      s += __shfl_xor(s, 1, 64);
      s += __shfl_xor(s, 2, 64);
      s += __shfl_xor(s, 4, 64);
      s += __shfl_xor(s, 8, 64);
      if (l15 == 0) atomicAdd(&lds_logit[wr + i * 16 + quad * 4 + r], s);
    }
  }
  __syncthreads();
  if (tid < BM) partial[(size_t)nb * MDIM + rowBase + tid] = lds_logit[tid];
}

// ---- softmax over L=1024 per batch ----
__global__ __launch_bounds__(256) void softmax_kernel(const float* __restrict__ partial,
                                                      const float* __restrict__ b_full,
                                                      float* __restrict__ att_out) {
  const int b = blockIdx.x, tid = threadIdx.x;
  const int lane = tid & 63, wid = tid >> 6;
  __shared__ float red[4];
  const float bf0 = b_full[0];
  float v[4];
  float m = -3.4e38f;
#pragma unroll
  for (int c = 0; c < 4; c++) {
    const int idx = b * 1024 + c * 256 + tid;
    float s = partial[idx] + partial[MDIM + idx] + partial[2 * MDIM + idx] +
              partial[3 * MDIM + idx] + bf0;
    v[c] = s;
    m = fmaxf(m, s);
  }
#pragma unroll
  for (int o = 1; o < 64; o <<= 1) m = fmaxf(m, __shfl_xor(m, o, 64));
  if (lane == 0) red[wid] = m;
  __syncthreads();
  m = fmaxf(fmaxf(red[0], red[1]), fmaxf(red[2], red[3]));
  __syncthreads();
  float s = 0.f;
#pragma unroll
  for (int c = 0; c < 4; c++) {
    v[c] = expf(v[c] - m);
    s += v[c];
  }
#pragma unroll
  for (int o = 1; o < 64; o <<= 1) s += __shfl_xor(s, o, 64);
  if (lane == 0) red[wid] = s;
  __syncthreads();
  const float inv = 1.0f / (red[0] + red[1] + red[2] + red[3]);
#pragma unroll
  for (int c = 0; c < 4; c++) att_out[b * 1024 + c * 256 + tid] = v[c] * inv;
}

// ---- context partials: 2048 blocks = 64b x 2ec x 16lc ----
__global__ __launch_bounds__(256) void ctx_partial_a(const float* __restrict__ enc,
                                                     const float* __restrict__ att,
                                                     float* __restrict__ ctxp) {
  const int x = blockIdx.x;
  const int lc = x & 15, ec = (x >> 4) & 1, b = x >> 5;
  const int tid = threadIdx.x;
  __shared__ float aw[64];
  if (tid < 64) aw[tid] = att[b * 1024 + lc * 64 + tid];
  __syncthreads();
  const int e0 = ec * 1024 + tid * 4;
  float4 acc = {0.f, 0.f, 0.f, 0.f};
  const float* base = enc + (size_t)b * 1024 * 2048 + (size_t)(lc * 64) * 2048 + e0;
#pragma unroll 16
  for (int l = 0; l < 64; l++) {
    const float w = aw[l];
    const float4 v = *(const float4*)(base + (size_t)l * 2048);
    acc.x += w * v.x;
    acc.y += w * v.y;
    acc.z += w * v.z;
    acc.w += w * v.w;
  }
  *(float4*)(ctxp + (size_t)lc * 131072 + b * 2048 + e0) = acc;
}

__global__ __launch_bounds__(256) void ctx_reduce_a(const float* __restrict__ ctxp,
                                                    float* __restrict__ out) {
  const int i = blockIdx.x * 256 + threadIdx.x;  // 131072
  float s = 0.f;
#pragma unroll
  for (int lc = 0; lc < 16; lc++) s += ctxp[(size_t)lc * 131072 + i];
  out[i] = s;
}

// ---- Tier B context ----
__global__ __launch_bounds__(256) void ctx_partial_b(const float* __restrict__ enc,
                                                     const float* __restrict__ att,
                                                     float* __restrict__ ctxp) {
  const int x = blockIdx.x;
  const int lc = x & 3, ec = (x >> 2) & 1, b = x >> 3;
  const int tid = threadIdx.x;
  __shared__ float aw[256];
  aw[tid] = att[b * 1024 + lc * 256 + tid];
  __syncthreads();
  const int e0 = ec * 1024 + tid * 4;
  float4 acc = {0.f, 0.f, 0.f, 0.f};
  const float* base = enc + (size_t)b * 1024 * 2048 + (size_t)(lc * 256) * 2048 + e0;
#pragma unroll 4
  for (int l = 0; l < 256; l++) {
    const float w = aw[l];
    const float4 v = *(const float4*)(base + (size_t)l * 2048);
    acc.x += w * v.x;
    acc.y += w * v.y;
    acc.z += w * v.z;
    acc.w += w * v.w;
  }
  *(float4*)(ctxp + (size_t)lc * 131072 + b * 2048 + e0) = acc;
}

__global__ __launch_bounds__(256) void ctx_reduce_b(const float* __restrict__ ctxp,
                                                    float* __restrict__ out) {
  const int i = blockIdx.x * 256 + threadIdx.x;
  out[i] = ctxp[i] + ctxp[131072 + i] + ctxp[262144 + i] + ctxp[393216 + i];
}

extern "C" void kernel_launch(void* const* d_in, const int* in_sizes, int n_in,
                              void* d_out, int out_size, void* d_ws, size_t ws_size,
                              hipStream_t stream) {
  const float* enc    = (const float*)d_in[0];
  const float* dec    = (const float*)d_in[1];
  const float* W_enc  = (const float*)d_in[2];
  const float* b_enc  = (const float*)d_in[3];
  const float* W_dec  = (const float*)d_in[4];
  const float* b_dec  = (const float*)d_in[5];
  const float* W_full = (const float*)d_in[6];
  const float* b_full = (const float*)d_in[7];
  float* out = (float*)d_out;
  char* ws = (char*)d_ws;

  const size_t MB = 1u << 20;
  // Fused path layout (no aliasing, no encb):
  // [0,2MB) Bp; [2MB,+128KB) att2; [2MB+128KB,+1MB) partial; [4MB,12MB) ctxp
  const size_t needF = 16 * MB;

  if (ws_size >= needF) {
    u16* Bp = (u16*)ws;
    float* att2 = (float*)(ws + 2 * MB);
    float* partial = (float*)(ws + 2 * MB + 128 * 1024);
    float* ctxp = (float*)(ws + 4 * MB);

    wenc_pack<<<512, 256, 0, stream>>>(W_enc, Bp);
    att2_kernel<<<128, 256, 0, stream>>>(dec, W_dec, b_dec, b_enc, att2);
    gemm_logits_f<<<2048, 256, 0, stream>>>(enc, Bp, att2, W_full, partial);
    softmax_kernel<<<64, 256, 0, stream>>>(partial, b_full, out + 131072);
    ctx_partial_a<<<2048, 256, 0, stream>>>(enc, out + 131072, ctxp);
    ctx_reduce_a<<<512, 256, 0, stream>>>(ctxp, out);
  } else {
    // Tier B: [0,2MB) WT / ctxp alias; [2MB,+128KB) att2; then partial
    u16* WT = (u16*)ws;
    float* ctxp = (float*)ws;
    float* att2 = (float*)(ws + 2 * MB);
    float* partial = (float*)(ws + 2 * MB + 128 * 1024);

    wenc_t<<<512, 256, 0, stream>>>(W_enc, WT);
    att2_kernel<<<128, 256, 0, stream>>>(dec, W_dec, b_dec, b_enc, att2);
    gemm_logits_b<<<2048, 256, 0, stream>>>(enc, WT, att2, W_full, partial);
    softmax_kernel<<<64, 256, 0, stream>>>(partial, b_full, out + 131072);
    ctx_partial_b<<<512, 256, 0, stream>>>(enc, out + 131072, ctxp);
    ctx_reduce_b<<<512, 256, 0, stream>>>(ctxp, out);
  }
}

// Round 15
// 922.670 us; speedup vs baseline: 1.1669x; 1.0417x over previous
//
#include <hip/hip_runtime.h>

typedef unsigned short u16;
typedef unsigned int u32;
typedef __bf16 bf16x8 __attribute__((ext_vector_type(8)));
typedef float f32x4 __attribute__((ext_vector_type(4)));

#define BM 128
#define BN 128
#define BK 64     // fused-GEMM K-tile
#define BKB 32    // Tier-B K-tile
#define KDIM 2048
#define NDIM 512
#define MDIM 65536
#define LROW 40   // Tier-B padded LDS row (ushorts)

__device__ __forceinline__ u16 f2bf(float f) {
  u32 u = __float_as_uint(f);
  u += 0x7FFFu + ((u >> 16) & 1u);   // round-to-nearest-even
  return (u16)(u >> 16);
}

// ---- W_enc (2048x512 f32) -> WT (512x2048 bf16), Tier-B only ----
__global__ __launch_bounds__(256) void wenc_t(const float* __restrict__ W, u16* __restrict__ WT) {
  const int n = blockIdx.x;  // 0..511
  for (int k = threadIdx.x; k < KDIM; k += 256)
    WT[n * KDIM + k] = f2bf(W[k * NDIM + n]);
}

// ---- W_enc -> Bp packed in MFMA B-fragment order ----
// u16 flat index: (((g16*32 + kk)*2 + h)*64 + lane)*8 ; lane=(quad<<4)|l15
// element j of lane's 8: B[n = g16*16 + l15][k = kk*64 + h*32 + quad*8 + j]
__global__ __launch_bounds__(256) void wenc_pack(const float* __restrict__ W,
                                                 u16* __restrict__ Bp) {
  const int t = blockIdx.x * 256 + threadIdx.x;  // 0..131071 (uint4 index)
  const int lane = t & 63;
  const int h = (t >> 6) & 1;
  const int kk = (t >> 7) & 31;
  const int g16 = t >> 12;
  const int l15 = lane & 15, quad = lane >> 4;
  const int n = g16 * 16 + l15;
  const int k0 = kk * 64 + h * 32 + quad * 8;
  u16 o[8];
#pragma unroll
  for (int j = 0; j < 8; j++) o[j] = f2bf(W[(size_t)(k0 + j) * NDIM + n]);
  *(uint4*)(Bp + (size_t)t * 8) = *(const uint4*)o;
}

// ---- att2[b,a] = dec[b,:]@W_dec[:,a] + b_dec[a] + b_enc[a] ----
__global__ __launch_bounds__(256) void att2_kernel(const float* __restrict__ dec,
                                                   const float* __restrict__ Wd,
                                                   const float* __restrict__ bd,
                                                   const float* __restrict__ be,
                                                   float* __restrict__ att2) {
  const int idx = blockIdx.x * 256 + threadIdx.x;  // 32768
  const int b = idx >> 9, a = idx & 511;
  float s = bd[a] + be[a];
  const float* dp = dec + b * 512;
#pragma unroll 8
  for (int d = 0; d < 512; d++) s += dp[d] * Wd[d * NDIM + a];
  att2[idx] = s;
}

// ---- Fused GEMM, single-barrier double-buffered LDS.
// Iter k: {B-frag L2 loads; convert+ds_write -> As[p]; prefetch A(k+1); barrier;
// ds_read As[p]; MFMA}. Buffer reuse at distance 2 is fenced by the intervening
// collective barrier (any wave passing barrier k finished its reads of iters
// k-1 and k-2 by program order) -> race-free with HALF the barriers (32 vs 64).
// Arithmetic identical to the verified r12 kernel -> bit-identical logits.
__global__ __launch_bounds__(256) void gemm_logits_f(const float* __restrict__ A,   // enc 65536x2048 f32
                                                     const u16* __restrict__ Bp,    // packed 2MB
                                                     const float* __restrict__ att2,
                                                     const float* __restrict__ Wfull,
                                                     float* __restrict__ partial) {
  __shared__ u16 As[2][BM * BK];   // 2 x 16 KB
  __shared__ float lds_logit[BM];

  const int tid = threadIdx.x;
  // XCD swizzle: flat = x + 8*(nb + 4*g), mb = g*8 + x
  const int flat = blockIdx.x;           // 0..2047
  const int x = flat & 7;
  const int nb = (flat >> 3) & 3;
  const int mb = ((flat >> 5) << 3) + x; // 0..511
  const int rowBase = mb * BM;
  const int colBase = nb * BN;
  const int b = rowBase >> 10;

  if (tid < BM) lds_logit[tid] = 0.f;

  const int lane = tid & 63, wid = tid >> 6;
  const int wr = (wid >> 1) * 64, wc = (wid & 1) * 64;
  const int quad = lane >> 4, l15 = lane & 15;

  float att2v[4], wfv[4];
#pragma unroll
  for (int j = 0; j < 4; j++) {
    const int g = colBase + wc + j * 16 + l15;
    att2v[j] = att2[b * NDIM + g];
    wfv[j] = Wfull[g];
  }

  // A staging: chunk c = s*256+tid -> row r=c>>3, stored k-chunk c&7,
  // global k-chunk g=(c&7)^(r&7)  (same mapping as the verified kernel)
  const float* AgF[4];
  int offD[4];
#pragma unroll
  for (int s = 0; s < 4; s++) {
    const int c = s * 256 + tid;
    const int r = c >> 3;
    const int g = (c & 7) ^ (r & 7);
    AgF[s] = A + (size_t)(rowBase + r) * KDIM + g * 8;
    offD[s] = c * 8;
  }

  const int g16_0 = (colBase + wc) >> 4;
  const uint4* BpV = (const uint4*)Bp;

  f32x4 acc[4][4];
#pragma unroll
  for (int i = 0; i < 4; i++)
#pragma unroll
    for (int j = 0; j < 4; j++) acc[i][j] = (f32x4)0.f;

  // fp32 prefetch registers (8 x float4 = 32 VGPR)
  float4 pa0[4], pa1[4];
  auto loadA = [&](int ko) {
#pragma unroll
    for (int s = 0; s < 4; s++) {
      pa0[s] = *(const float4*)(AgF[s] + ko);
      pa1[s] = *(const float4*)(AgF[s] + ko + 4);
    }
  };
  loadA(0);

  int p = 0;
  for (int kk = 0; kk < KDIM / BK; kk++) {
    // B frags first: L2 latency hides under convert+store+barrier
    uint4 braw[2][4];
#pragma unroll
    for (int h = 0; h < 2; h++)
#pragma unroll
      for (int j = 0; j < 4; j++)
        braw[h][j] = BpV[(g16_0 + j) * 4096 + kk * 128 + h * 64 + lane];
    // convert + store A chunks into As[p] (same bytes/addresses as verified)
    u16* dstb = &As[p][0];
#pragma unroll
    for (int s = 0; s < 4; s++) {
      uint4 o;
      o.x = f2bf(pa0[s].x) | ((u32)f2bf(pa0[s].y) << 16);
      o.y = f2bf(pa0[s].z) | ((u32)f2bf(pa0[s].w) << 16);
      o.z = f2bf(pa1[s].x) | ((u32)f2bf(pa1[s].y) << 16);
      o.w = f2bf(pa1[s].z) | ((u32)f2bf(pa1[s].w) << 16);
      *(uint4*)(dstb + offD[s]) = o;
    }
    if (kk + 1 < KDIM / BK) loadA((kk + 1) * BK);  // prefetch next fp32 tile
    __syncthreads();   // write->read fence for As[p]; also fences reuse at dist 2

    bf16x8 afr[2][4];
#pragma unroll
    for (int h = 0; h < 2; h++)
#pragma unroll
      for (int i = 0; i < 4; i++) {
        const int m = wr + i * 16 + l15;
        afr[h][i] = *(const bf16x8*)&As[p][m * BK + ((((h << 2) | quad) ^ (l15 & 7)) << 3)];
      }
#pragma unroll
    for (int h = 0; h < 2; h++)
#pragma unroll
      for (int i = 0; i < 4; i++)
#pragma unroll
        for (int j = 0; j < 4; j++)
          acc[i][j] = __builtin_amdgcn_mfma_f32_16x16x32_bf16(
              afr[h][i], *(const bf16x8*)&braw[h][j], acc[i][j], 0, 0, 0);
    p ^= 1;
  }

#pragma unroll
  for (int i = 0; i < 4; i++) {
#pragma unroll
    for (int r = 0; r < 4; r++) {
      float s = 0.f;
#pragma unroll
      for (int j = 0; j < 4; j++) {
        float v = acc[i][j][r] + att2v[j];
        v = v > 0.f ? v : 0.f;
        s += v * wfv[j];
      }
      s += __shfl_xor(s, 1, 64);
      s += __shfl_xor(s, 2, 64);
      s += __shfl_xor(s, 4, 64);
      s += __shfl_xor(s, 8, 64);
      if (l15 == 0) atomicAdd(&lds_logit[wr + i * 16 + quad * 4 + r], s);
    }
  }
  __syncthreads();
  if (tid < BM) partial[(size_t)nb * MDIM + rowBase + tid] = lds_logit[tid];
}

// ---- Tier B fallback GEMM (inline fp32->bf16 staging, BKB=32) ----
__global__ __launch_bounds__(256, 2) void gemm_logits_b(const float* __restrict__ enc,
                                                        const u16* __restrict__ WT,
                                                        const float* __restrict__ att2,
                                                        const float* __restrict__ Wfull,
                                                        float* __restrict__ partial) {
  __shared__ u16 As[BM * LROW];
  __shared__ u16 Bs[BN * LROW];
  __shared__ float lds_logit[BM];

  const int tid = threadIdx.x;
  const int flat = blockIdx.x;           // 0..2047
  const int x = flat & 7;
  const int nb = (flat >> 3) & 3;
  const int mb = ((flat >> 5) << 3) + x; // 0..511
  const int rowBase = mb * BM, colBase = nb * BN;
  const int b = rowBase >> 10;
  if (tid < BM) lds_logit[tid] = 0.f;
  const int lane = tid & 63, wid = tid >> 6;
  const int wr = (wid >> 1) * 64, wc = (wid & 1) * 64;
  const int quad = lane >> 4, l15 = lane & 15;

  float att2v[4], wfv[4];
#pragma unroll
  for (int j = 0; j < 4; j++) {
    const int g = colBase + wc + j * 16 + l15;
    att2v[j] = att2[b * NDIM + g];
    wfv[j] = Wfull[g];
  }
  const int srow = tid >> 1, shalf = tid & 1;
  const float* Ag = enc + (size_t)(rowBase + srow) * KDIM + shalf * 16;
  const u16* Bg = WT + (size_t)(colBase + srow) * KDIM + shalf * 16;

  f32x4 acc[4][4];
#pragma unroll
  for (int i = 0; i < 4; i++)
#pragma unroll
    for (int j = 0; j < 4; j++) acc[i][j] = (f32x4)0.f;

  float4 a0, a1, a2, a3;
  uint4 bb0, bb1;
  auto loadA = [&](int k0) {
    const float* p = Ag + k0;
    a0 = *(const float4*)(p);
    a1 = *(const float4*)(p + 4);
    a2 = *(const float4*)(p + 8);
    a3 = *(const float4*)(p + 12);
  };
  auto loadB = [&](int k0) {
    const u16* p = Bg + k0;
    bb0 = *(const uint4*)(p);
    bb1 = *(const uint4*)(p + 8);
  };
  loadA(0);
  loadB(0);
  u16* AsW = &As[srow * LROW + shalf * 16];
  u16* BsW = &Bs[srow * LROW + shalf * 16];
  const u16* aRd = &As[(wr + l15) * LROW + quad * 8];
  const u16* bRd = &Bs[(wc + l15) * LROW + quad * 8];

  for (int kk = 0; kk < KDIM / BKB; kk++) {
    __syncthreads();
    u32 w0 = f2bf(a0.x) | ((u32)f2bf(a0.y) << 16);
    u32 w1 = f2bf(a0.z) | ((u32)f2bf(a0.w) << 16);
    u32 w2 = f2bf(a1.x) | ((u32)f2bf(a1.y) << 16);
    u32 w3 = f2bf(a1.z) | ((u32)f2bf(a1.w) << 16);
    u32 w4 = f2bf(a2.x) | ((u32)f2bf(a2.y) << 16);
    u32 w5 = f2bf(a2.z) | ((u32)f2bf(a2.w) << 16);
    u32 w6 = f2bf(a3.x) | ((u32)f2bf(a3.y) << 16);
    u32 w7 = f2bf(a3.z) | ((u32)f2bf(a3.w) << 16);
    *(uint4*)AsW = make_uint4(w0, w1, w2, w3);
    *(uint4*)(AsW + 8) = make_uint4(w4, w5, w6, w7);
    *(uint4*)BsW = bb0;
    *(uint4*)(BsW + 8) = bb1;
    __syncthreads();
    if (kk + 1 < KDIM / BKB) {
      loadA((kk + 1) * BKB);
      loadB((kk + 1) * BKB);
    }
    bf16x8 afr[4], bfr[4];
#pragma unroll
    for (int i = 0; i < 4; i++) afr[i] = *(const bf16x8*)(aRd + i * 16 * LROW);
#pragma unroll
    for (int j = 0; j < 4; j++) bfr[j] = *(const bf16x8*)(bRd + j * 16 * LROW);
#pragma unroll
    for (int i = 0; i < 4; i++)
#pragma unroll
      for (int j = 0; j < 4; j++)
        acc[i][j] = __builtin_amdgcn_mfma_f32_16x16x32_bf16(afr[i], bfr[j], acc[i][j], 0, 0, 0);
  }
#pragma unroll
  for (int i = 0; i < 4; i++) {
#pragma unroll
    for (int r = 0; r < 4; r++) {
      float s = 0.f;
#pragma unroll
      for (int j = 0; j < 4; j++) {
        float v = acc[i][j][r] + att2v[j];
        v = v > 0.f ? v : 0.f;
        s += v * wfv[j];
      }
      s += __shfl_xor(s, 1, 64);
      s += __shfl_xor(s, 2, 64);
      s += __shfl_xor(s, 4, 64);
      s += __shfl_xor(s, 8, 64);
      if (l15 == 0) atomicAdd(&lds_logit[wr + i * 16 + quad * 4 + r], s);
    }
  }
  __syncthreads();
  if (tid < BM) partial[(size_t)nb * MDIM + rowBase + tid] = lds_logit[tid];
}

// ---- softmax over L=1024 per batch ----
__global__ __launch_bounds__(256) void softmax_kernel(const float* __restrict__ partial,
                                                      const float* __restrict__ b_full,
                                                      float* __restrict__ att_out) {
  const int b = blockIdx.x, tid = threadIdx.x;
  const int lane = tid & 63, wid = tid >> 6;
  __shared__ float red[4];
  const float bf0 = b_full[0];
  float v[4];
  float m = -3.4e38f;
#pragma unroll
  for (int c = 0; c < 4; c++) {
    const int idx = b * 1024 + c * 256 + tid;
    float s = partial[idx] + partial[MDIM + idx] + partial[2 * MDIM + idx] +
              partial[3 * MDIM + idx] + bf0;
    v[c] = s;
    m = fmaxf(m, s);
  }
#pragma unroll
  for (int o = 1; o < 64; o <<= 1) m = fmaxf(m, __shfl_xor(m, o, 64));
  if (lane == 0) red[wid] = m;
  __syncthreads();
  m = fmaxf(fmaxf(red[0], red[1]), fmaxf(red[2], red[3]));
  __syncthreads();
  float s = 0.f;
#pragma unroll
  for (int c = 0; c < 4; c++) {
    v[c] = expf(v[c] - m);
    s += v[c];
  }
#pragma unroll
  for (int o = 1; o < 64; o <<= 1) s += __shfl_xor(s, o, 64);
  if (lane == 0) red[wid] = s;
  __syncthreads();
  const float inv = 1.0f / (red[0] + red[1] + red[2] + red[3]);
#pragma unroll
  for (int c = 0; c < 4; c++) att_out[b * 1024 + c * 256 + tid] = v[c] * inv;
}

// ---- context partials: 2048 blocks = 64b x 2ec x 16lc ----
__global__ __launch_bounds__(256) void ctx_partial_a(const float* __restrict__ enc,
                                                     const float* __restrict__ att,
                                                     float* __restrict__ ctxp) {
  const int x = blockIdx.x;
  const int lc = x & 15, ec = (x >> 4) & 1, b = x >> 5;
  const int tid = threadIdx.x;
  __shared__ float aw[64];
  if (tid < 64) aw[tid] = att[b * 1024 + lc * 64 + tid];
  __syncthreads();
  const int e0 = ec * 1024 + tid * 4;
  float4 acc = {0.f, 0.f, 0.f, 0.f};
  const float* base = enc + (size_t)b * 1024 * 2048 + (size_t)(lc * 64) * 2048 + e0;
#pragma unroll 16
  for (int l = 0; l < 64; l++) {
    const float w = aw[l];
    const float4 v = *(const float4*)(base + (size_t)l * 2048);
    acc.x += w * v.x;
    acc.y += w * v.y;
    acc.z += w * v.z;
    acc.w += w * v.w;
  }
  *(float4*)(ctxp + (size_t)lc * 131072 + b * 2048 + e0) = acc;
}

__global__ __launch_bounds__(256) void ctx_reduce_a(const float* __restrict__ ctxp,
                                                    float* __restrict__ out) {
  const int i = blockIdx.x * 256 + threadIdx.x;  // 131072
  float s = 0.f;
#pragma unroll
  for (int lc = 0; lc < 16; lc++) s += ctxp[(size_t)lc * 131072 + i];
  out[i] = s;
}

// ---- Tier B context ----
__global__ __launch_bounds__(256) void ctx_partial_b(const float* __restrict__ enc,
                                                     const float* __restrict__ att,
                                                     float* __restrict__ ctxp) {
  const int x = blockIdx.x;
  const int lc = x & 3, ec = (x >> 2) & 1, b = x >> 3;
  const int tid = threadIdx.x;
  __shared__ float aw[256];
  aw[tid] = att[b * 1024 + lc * 256 + tid];
  __syncthreads();
  const int e0 = ec * 1024 + tid * 4;
  float4 acc = {0.f, 0.f, 0.f, 0.f};
  const float* base = enc + (size_t)b * 1024 * 2048 + (size_t)(lc * 256) * 2048 + e0;
#pragma unroll 4
  for (int l = 0; l < 256; l++) {
    const float w = aw[l];
    const float4 v = *(const float4*)(base + (size_t)l * 2048);
    acc.x += w * v.x;
    acc.y += w * v.y;
    acc.z += w * v.z;
    acc.w += w * v.w;
  }
  *(float4*)(ctxp + (size_t)lc * 131072 + b * 2048 + e0) = acc;
}

__global__ __launch_bounds__(256) void ctx_reduce_b(const float* __restrict__ ctxp,
                                                    float* __restrict__ out) {
  const int i = blockIdx.x * 256 + threadIdx.x;
  out[i] = ctxp[i] + ctxp[131072 + i] + ctxp[262144 + i] + ctxp[393216 + i];
}

extern "C" void kernel_launch(void* const* d_in, const int* in_sizes, int n_in,
                              void* d_out, int out_size, void* d_ws, size_t ws_size,
                              hipStream_t stream) {
  const float* enc    = (const float*)d_in[0];
  const float* dec    = (const float*)d_in[1];
  const float* W_enc  = (const float*)d_in[2];
  const float* b_enc  = (const float*)d_in[3];
  const float* W_dec  = (const float*)d_in[4];
  const float* b_dec  = (const float*)d_in[5];
  const float* W_full = (const float*)d_in[6];
  const float* b_full = (const float*)d_in[7];
  float* out = (float*)d_out;
  char* ws = (char*)d_ws;

  const size_t MB = 1u << 20;
  // Fused path layout (no aliasing, no encb):
  // [0,2MB) Bp; [2MB,+128KB) att2; [2MB+128KB,+1MB) partial; [4MB,12MB) ctxp
  const size_t needF = 16 * MB;

  if (ws_size >= needF) {
    u16* Bp = (u16*)ws;
    float* att2 = (float*)(ws + 2 * MB);
    float* partial = (float*)(ws + 2 * MB + 128 * 1024);
    float* ctxp = (float*)(ws + 4 * MB);

    wenc_pack<<<512, 256, 0, stream>>>(W_enc, Bp);
    att2_kernel<<<128, 256, 0, stream>>>(dec, W_dec, b_dec, b_enc, att2);
    gemm_logits_f<<<2048, 256, 0, stream>>>(enc, Bp, att2, W_full, partial);
    softmax_kernel<<<64, 256, 0, stream>>>(partial, b_full, out + 131072);
    ctx_partial_a<<<2048, 256, 0, stream>>>(enc, out + 131072, ctxp);
    ctx_reduce_a<<<512, 256, 0, stream>>>(ctxp, out);
  } else {
    // Tier B: [0,2MB) WT / ctxp alias; [2MB,+128KB) att2; then partial
    u16* WT = (u16*)ws;
    float* ctxp = (float*)ws;
    float* att2 = (float*)(ws + 2 * MB);
    float* partial = (float*)(ws + 2 * MB + 128 * 1024);

    wenc_t<<<512, 256, 0, stream>>>(W_enc, WT);
    att2_kernel<<<128, 256, 0, stream>>>(dec, W_dec, b_dec, b_enc, att2);
    gemm_logits_b<<<2048, 256, 0, stream>>>(enc, WT, att2, W_full, partial);
    softmax_kernel<<<64, 256, 0, stream>>>(partial, b_full, out + 131072);
    ctx_partial_b<<<512, 256, 0, stream>>>(enc, out + 131072, ctxp);
    ctx_reduce_b<<<512, 256, 0, stream>>>(ctxp, out);
  }
}